// Round 5
// baseline (1599.403 us; speedup 1.0000x reference)
//
#include <hip/hip_runtime.h>

#define NROWS 100000
#define C_IN 16
#define C_OUT 32
#define KK 27
#define EPS 1e-5f
#define SLOPE 0.01f

#define NC (NROWS * C_OUT)   // 3,200,000 floats per [N,32] buffer

// stats layout (floats): [0..31] sum1, [32..63] sq1, [64..95] sumR, [96..127] sqR,
//                        [128..159] sum2, [160..191] sq2
#define ST_SUM1 0
#define ST_SQ1  32
#define ST_SUMR 64
#define ST_SQR  96
#define ST_SUM2 128
#define ST_SQ2  160

// ---------------- mask dtype detection: bool(u8) vs int32 ----------------
// If any byte at offset %4 != 0 within the first 4KB is nonzero, layout is u8.
__global__ __launch_bounds__(256) void k_detect(const unsigned char* __restrict__ mb,
                                                int* __restrict__ flag) {
  __shared__ int found;
  if (threadIdx.x == 0) found = 0;
  __syncthreads();
  int f = 0;
  for (int i = threadIdx.x; i < 4096; i += 256)
    if ((i & 3) != 0 && mb[i] != 0) f = 1;
  if (f) atomicOr(&found, 1);
  __syncthreads();
  if (threadIdx.x == 0) *flag = found;  // 1 => u8 layout, 0 => int32 layout
}

// pack 27 mask bits per row into one uint32
__global__ __launch_bounds__(256) void k_canon(const void* __restrict__ mask,
                                               const int* __restrict__ flag,
                                               unsigned* __restrict__ umask) {
  const int n = blockIdx.x * 256 + threadIdx.x;
  if (n >= NROWS) return;
  unsigned bits = 0;
  if (*flag) {
    const unsigned char* m = (const unsigned char*)mask + (size_t)n * KK;
    for (int k = 0; k < KK; ++k) bits |= (unsigned)(m[k] != 0) << k;
  } else {
    const int* m = (const int*)mask + (size_t)n * KK;
    for (int k = 0; k < KK; ++k) bits |= (unsigned)(m[k] != 0) << k;
  }
  umask[n] = bits;
}

// ---------------- K1: conv1 (features,W1) + residual (features@Win) + stats ----------------
__global__ __launch_bounds__(256) void k_conv1(
    const float* __restrict__ features, const int* __restrict__ neighbors,
    const unsigned* __restrict__ umask, const float* __restrict__ W1,
    const float* __restrict__ Win,
    float* __restrict__ y1, float* __restrict__ rbuf, float* __restrict__ stats) {
  __shared__ float sW1[KK * C_IN * C_OUT];   // 13824 floats = 54 KB
  __shared__ float sWin[C_IN * C_OUT];       // 2 KB
  const int tid = threadIdx.x;
  for (int i = tid; i < KK * C_IN * C_OUT; i += 256) sW1[i] = W1[i];
  for (int i = tid; i < C_IN * C_OUT; i += 256) sWin[i] = Win[i];
  __syncthreads();

  const int n = blockIdx.x * 256 + tid;
  const bool valid = n < NROWS;

  float acc[C_OUT], accR[C_OUT];
#pragma unroll
  for (int d = 0; d < C_OUT; ++d) { acc[d] = 0.f; accR[d] = 0.f; }

  if (valid) {
    float f[C_IN];
    const float4* fp = reinterpret_cast<const float4*>(features + (size_t)n * C_IN);
#pragma unroll
    for (int j = 0; j < C_IN / 4; ++j) {
      float4 v = fp[j];
      f[4 * j] = v.x; f[4 * j + 1] = v.y; f[4 * j + 2] = v.z; f[4 * j + 3] = v.w;
    }
    // residual: features @ Win
#pragma unroll
    for (int c = 0; c < C_IN; ++c) {
#pragma unroll
      for (int d = 0; d < C_OUT; ++d) accR[d] += f[c] * sWin[c * C_OUT + d];
    }
    const int* nb = neighbors + (size_t)n * KK;
    const unsigned um = umask[n];
    for (int k = 0; k < KK; ++k) {
      if ((um >> k) & 1u) {
        const int idx = nb[k];
        float g[C_IN];
        const float4* gp = reinterpret_cast<const float4*>(features + (size_t)idx * C_IN);
#pragma unroll
        for (int j = 0; j < C_IN / 4; ++j) {
          float4 v = gp[j];
          g[4 * j] = v.x; g[4 * j + 1] = v.y; g[4 * j + 2] = v.z; g[4 * j + 3] = v.w;
        }
        const float* w = &sW1[k * C_IN * C_OUT];
#pragma unroll
        for (int c = 0; c < C_IN; ++c) {
#pragma unroll
          for (int d = 0; d < C_OUT; ++d) acc[d] += g[c] * w[c * C_OUT + d];
        }
      }
    }
    float4* yp = reinterpret_cast<float4*>(y1 + (size_t)n * C_OUT);
    float4* rp = reinterpret_cast<float4*>(rbuf + (size_t)n * C_OUT);
#pragma unroll
    for (int j = 0; j < C_OUT / 4; ++j) {
      yp[j] = make_float4(acc[4 * j], acc[4 * j + 1], acc[4 * j + 2], acc[4 * j + 3]);
      rp[j] = make_float4(accR[4 * j], accR[4 * j + 1], accR[4 * j + 2], accR[4 * j + 3]);
    }
  }

  // per-wave reduction of sum / sumsq for y1 and residual; one atomic per wave per channel
  const int lane = tid & 63;
#pragma unroll
  for (int d = 0; d < C_OUT; ++d) {
    float v = acc[d], s = acc[d] * acc[d];
    float vr = accR[d], sr = accR[d] * accR[d];
#pragma unroll
    for (int m = 32; m >= 1; m >>= 1) {
      v += __shfl_xor(v, m); s += __shfl_xor(s, m);
      vr += __shfl_xor(vr, m); sr += __shfl_xor(sr, m);
    }
    if (lane == 0) {
      atomicAdd(&stats[ST_SUM1 + d], v);
      atomicAdd(&stats[ST_SQ1 + d], s);
      atomicAdd(&stats[ST_SUMR + d], vr);
      atomicAdd(&stats[ST_SQR + d], sr);
    }
  }
}

// ---------------- K2: x1 = lrelu(bn(y1)) ----------------
__global__ __launch_bounds__(256) void k_bn1(
    const float* __restrict__ y1, const float* __restrict__ stats,
    const float* __restrict__ g1, const float* __restrict__ b1,
    float* __restrict__ x1) {
  const int i = blockIdx.x * 256 + threadIdx.x;  // float4 index
  if (i >= NC / 4) return;
  const int d0 = (i * 4) & (C_OUT - 1);
  float4 v = reinterpret_cast<const float4*>(y1)[i];
  float vv[4] = {v.x, v.y, v.z, v.w};
  float o[4];
#pragma unroll
  for (int j = 0; j < 4; ++j) {
    const int d = d0 + j;
    const float mean = stats[ST_SUM1 + d] * (1.0f / NROWS);
    const float var = stats[ST_SQ1 + d] * (1.0f / NROWS) - mean * mean;
    const float inv = 1.0f / sqrtf(var + EPS);
    const float x = (vv[j] - mean) * inv * g1[d] + b1[d];
    o[j] = x >= 0.f ? x : SLOPE * x;
  }
  reinterpret_cast<float4*>(x1)[i] = make_float4(o[0], o[1], o[2], o[3]);
}

// ---------------- K3: conv2 (x1,W2) + stats ----------------
#define KCH 14
__global__ __launch_bounds__(256) void k_conv2(
    const float* __restrict__ x1, const int* __restrict__ neighbors,
    const unsigned* __restrict__ umask, const float* __restrict__ W2,
    float* __restrict__ y2, float* __restrict__ stats) {
  __shared__ float sW[KCH * C_OUT * C_OUT];  // 14336 floats = 56 KB
  const int tid = threadIdx.x;
  const int n = blockIdx.x * 256 + tid;
  const bool valid = n < NROWS;
  const unsigned um = valid ? umask[n] : 0u;

  float acc[C_OUT];
#pragma unroll
  for (int d = 0; d < C_OUT; ++d) acc[d] = 0.f;

  for (int k0 = 0; k0 < KK; k0 += KCH) {
    const int kn = (KK - k0) < KCH ? (KK - k0) : KCH;
    __syncthreads();
    for (int i = tid; i < kn * C_OUT * C_OUT; i += 256)
      sW[i] = W2[k0 * C_OUT * C_OUT + i];
    __syncthreads();
    if (valid) {
      for (int k = 0; k < kn; ++k) {
        const int kk = k0 + k;
        if ((um >> kk) & 1u) {
          const int idx = neighbors[(size_t)n * KK + kk];
          float g[C_OUT];
          const float4* gp = reinterpret_cast<const float4*>(x1 + (size_t)idx * C_OUT);
#pragma unroll
          for (int j = 0; j < C_OUT / 4; ++j) {
            float4 v = gp[j];
            g[4 * j] = v.x; g[4 * j + 1] = v.y; g[4 * j + 2] = v.z; g[4 * j + 3] = v.w;
          }
          const float* w = &sW[k * C_OUT * C_OUT];
#pragma unroll
          for (int c = 0; c < C_OUT; ++c) {
#pragma unroll
            for (int d = 0; d < C_OUT; ++d) acc[d] += g[c] * w[c * C_OUT + d];
          }
        }
      }
    }
  }

  if (valid) {
    float4* yp = reinterpret_cast<float4*>(y2 + (size_t)n * C_OUT);
#pragma unroll
    for (int j = 0; j < C_OUT / 4; ++j)
      yp[j] = make_float4(acc[4 * j], acc[4 * j + 1], acc[4 * j + 2], acc[4 * j + 3]);
  }

  const int lane = tid & 63;
#pragma unroll
  for (int d = 0; d < C_OUT; ++d) {
    float v = acc[d], s = acc[d] * acc[d];
#pragma unroll
    for (int m = 32; m >= 1; m >>= 1) {
      v += __shfl_xor(v, m); s += __shfl_xor(s, m);
    }
    if (lane == 0) {
      atomicAdd(&stats[ST_SUM2 + d], v);
      atomicAdd(&stats[ST_SQ2 + d], s);
    }
  }
}

// ---------------- K4: out = lrelu(bn(y2) + bn(r)) ----------------
__global__ __launch_bounds__(256) void k_out(
    const float* __restrict__ y2, const float* __restrict__ rbuf,
    const float* __restrict__ stats,
    const float* __restrict__ g2, const float* __restrict__ b2,
    const float* __restrict__ gin, const float* __restrict__ bin_,
    float* __restrict__ out) {
  const int i = blockIdx.x * 256 + threadIdx.x;  // float4 index
  if (i >= NC / 4) return;
  const int d0 = (i * 4) & (C_OUT - 1);
  float4 v2 = reinterpret_cast<const float4*>(y2)[i];
  float4 vr = reinterpret_cast<const float4*>(rbuf)[i];
  float a2[4] = {v2.x, v2.y, v2.z, v2.w};
  float ar[4] = {vr.x, vr.y, vr.z, vr.w};
  float o[4];
#pragma unroll
  for (int j = 0; j < 4; ++j) {
    const int d = d0 + j;
    const float m2 = stats[ST_SUM2 + d] * (1.0f / NROWS);
    const float va2 = stats[ST_SQ2 + d] * (1.0f / NROWS) - m2 * m2;
    const float i2 = 1.0f / sqrtf(va2 + EPS);
    const float mr = stats[ST_SUMR + d] * (1.0f / NROWS);
    const float var_r = stats[ST_SQR + d] * (1.0f / NROWS) - mr * mr;
    const float ir = 1.0f / sqrtf(var_r + EPS);
    const float xa = (a2[j] - m2) * i2 * g2[d] + b2[d];
    const float xr = (ar[j] - mr) * ir * gin[d] + bin_[d];
    const float s = xa + xr;
    o[j] = s >= 0.f ? s : SLOPE * s;
  }
  reinterpret_cast<float4*>(out)[i] = make_float4(o[0], o[1], o[2], o[3]);
}

extern "C" void kernel_launch(void* const* d_in, const int* in_sizes, int n_in,
                              void* d_out, int out_size, void* d_ws, size_t ws_size,
                              hipStream_t stream) {
  (void)in_sizes; (void)n_in; (void)out_size; (void)ws_size;
  const float* features = (const float*)d_in[0];
  const int* neighbors = (const int*)d_in[1];
  const void* mask = d_in[2];
  const float* W1 = (const float*)d_in[3];
  const float* g1 = (const float*)d_in[4];
  const float* b1 = (const float*)d_in[5];
  const float* W2 = (const float*)d_in[6];
  const float* g2 = (const float*)d_in[7];
  const float* b2 = (const float*)d_in[8];
  const float* Win = (const float*)d_in[9];
  const float* gin = (const float*)d_in[10];
  const float* bin_ = (const float*)d_in[11];
  float* out = (float*)d_out;

  // workspace layout (floats): x1 [NC], rbuf [NC], stats [192], flag [1 int],
  // umask [NROWS uints]. y1/y2 live in d_out (consumed before overwritten).
  float* ws = (float*)d_ws;
  float* x1 = ws;
  float* rbuf = ws + (size_t)NC;
  float* stats = ws + 2 * (size_t)NC;
  int* flag = (int*)(ws + 2 * (size_t)NC + 192);
  unsigned* umask = (unsigned*)(ws + 2 * (size_t)NC + 256);

  hipMemsetAsync(stats, 0, 192 * sizeof(float), stream);

  const int convBlocks = (NROWS + 255) / 256;       // 391
  const int ewBlocks = (NC / 4 + 255) / 256;        // 3125

  k_detect<<<1, 256, 0, stream>>>((const unsigned char*)mask, flag);
  k_canon<<<convBlocks, 256, 0, stream>>>(mask, flag, umask);
  k_conv1<<<convBlocks, 256, 0, stream>>>(features, neighbors, umask, W1, Win,
                                          out /*y1*/, rbuf, stats);
  k_bn1<<<ewBlocks, 256, 0, stream>>>(out /*y1*/, stats, g1, b1, x1);
  k_conv2<<<convBlocks, 256, 0, stream>>>(x1, neighbors, umask, W2, out /*y2*/, stats);
  k_out<<<ewBlocks, 256, 0, stream>>>(out /*y2*/, rbuf, stats, g2, b2, gin, bin_, out);
}

// Round 7
// 1452.863 us; speedup vs baseline: 1.1009x; 1.1009x over previous
//
#include <hip/hip_runtime.h>

#define NROWS 100000
#define C_IN 16
#define C_OUT 32
#define KK 27
#define EPS 1e-5f
#define SLOPE 0.01f

#define NC (NROWS * C_OUT)   // 3,200,000 floats per [N,32] buffer

// stats layout (floats): sum1, sq1, sumR, sqR, sum2, sq2 (32 each)
#define ST_SUM1 0
#define ST_SQ1  32
#define ST_SUMR 64
#define ST_SQR  96
#define ST_SUM2 128
#define ST_SQ2  160

typedef unsigned short u16;

__device__ __forceinline__ unsigned bf16rne(float x) {
  unsigned u = __float_as_uint(x);
  return (u + 0x7fffu + ((u >> 16) & 1u)) >> 16;
}
__device__ __forceinline__ unsigned pack2(float lo, float hi) {
  return bf16rne(lo) | (bf16rne(hi) << 16);
}
__device__ __forceinline__ float blo(unsigned p) { return __uint_as_float(p << 16); }
__device__ __forceinline__ float bhi(unsigned p) { return __uint_as_float(p & 0xffff0000u); }

// ---------------- mask dtype detection: bool(u8) vs int32 ----------------
__global__ __launch_bounds__(256) void k_detect(const unsigned char* __restrict__ mb,
                                                int* __restrict__ flag) {
  __shared__ int found;
  if (threadIdx.x == 0) found = 0;
  __syncthreads();
  int f = 0;
  for (int i = threadIdx.x; i < 4096; i += 256)
    if ((i & 3) != 0 && mb[i] != 0) f = 1;
  if (f) atomicOr(&found, 1);
  __syncthreads();
  if (threadIdx.x == 0) *flag = found;  // 1 => u8 layout, 0 => int32 layout
}

// ---------------- canon: pack mask bits, bf16 feature table, transpose neighbors --------
__global__ __launch_bounds__(256) void k_canon(
    const void* __restrict__ mask, const int* __restrict__ flag,
    const int* __restrict__ neighbors, const float* __restrict__ features,
    unsigned* __restrict__ umask, u16* __restrict__ featb, int* __restrict__ nbT) {
  const int n = blockIdx.x * 256 + threadIdx.x;
  if (n >= NROWS) return;
  unsigned bits = 0;
  if (*flag) {
    const unsigned char* m = (const unsigned char*)mask + (size_t)n * KK;
#pragma unroll
    for (int k = 0; k < KK; ++k) bits |= (unsigned)(m[k] != 0) << k;
  } else {
    const int* m = (const int*)mask + (size_t)n * KK;
#pragma unroll
    for (int k = 0; k < KK; ++k) bits |= (unsigned)(m[k] != 0) << k;
  }
  umask[n] = bits;

  const int* nb = neighbors + (size_t)n * KK;
#pragma unroll
  for (int k = 0; k < KK; ++k) nbT[(size_t)k * NROWS + n] = nb[k];

  const float4* fp = reinterpret_cast<const float4*>(features + (size_t)n * C_IN);
  float f[C_IN];
#pragma unroll
  for (int j = 0; j < C_IN / 4; ++j) {
    float4 v = fp[j];
    f[4 * j] = v.x; f[4 * j + 1] = v.y; f[4 * j + 2] = v.z; f[4 * j + 3] = v.w;
  }
  uint4 r0, r1;
  r0.x = pack2(f[0], f[1]);  r0.y = pack2(f[2], f[3]);
  r0.z = pack2(f[4], f[5]);  r0.w = pack2(f[6], f[7]);
  r1.x = pack2(f[8], f[9]);  r1.y = pack2(f[10], f[11]);
  r1.z = pack2(f[12], f[13]); r1.w = pack2(f[14], f[15]);
  uint4* fb = reinterpret_cast<uint4*>(featb + (size_t)n * C_IN);
  fb[0] = r0; fb[1] = r1;
}

// ---------------- conv1: gather bf16 feats, scalar f32 weights, + residual + stats -------
// block 256 = 4 waves; wave w handles rows [bid*64 .. bid*64+63], channels [w*8 .. w*8+7]
__global__ __launch_bounds__(256, 4) void k_conv1(
    const float* __restrict__ features, const u16* __restrict__ featb,
    const int* __restrict__ nbT, const unsigned* __restrict__ umask,
    const float* __restrict__ W1, const float* __restrict__ Win,
    float* __restrict__ y1, float* __restrict__ rbuf, float* __restrict__ stats) {
  const int tid = threadIdx.x;
  const int lane = tid & 63;
  const int d0 = __builtin_amdgcn_readfirstlane((tid >> 6) * 8);  // wave-uniform
  const int row = blockIdx.x * 64 + lane;
  const bool valid = row < NROWS;

  float acc[8], accR[8];
#pragma unroll
  for (int j = 0; j < 8; ++j) { acc[j] = 0.f; accR[j] = 0.f; }

  if (valid) {
    // residual slice: f32 features @ Win[:, d0:d0+8]
    {
      const float4* fp = reinterpret_cast<const float4*>(features + (size_t)row * C_IN);
      float f[C_IN];
#pragma unroll
      for (int j = 0; j < C_IN / 4; ++j) {
        float4 v = fp[j];
        f[4 * j] = v.x; f[4 * j + 1] = v.y; f[4 * j + 2] = v.z; f[4 * j + 3] = v.w;
      }
#pragma unroll
      for (int c = 0; c < C_IN; ++c) {
        const float* wr = Win + c * C_OUT + d0;   // uniform addr -> s_load
#pragma unroll
        for (int j = 0; j < 8; ++j) accR[j] = fmaf(f[c], wr[j], accR[j]);
      }
    }

    const unsigned um = umask[row];
#pragma unroll 3
    for (int k = 0; k < KK; ++k) {
      const int idx = nbT[(size_t)k * NROWS + row];
      const unsigned sel = 0u - ((um >> k) & 1u);  // 0 or all-ones, branchless
      const uint4* gp = reinterpret_cast<const uint4*>(featb + (size_t)idx * C_IN);
      uint4 p0 = gp[0], p1 = gp[1];
      p0.x &= sel; p0.y &= sel; p0.z &= sel; p0.w &= sel;
      p1.x &= sel; p1.y &= sel; p1.z &= sel; p1.w &= sel;
      float g[C_IN];
      g[0] = blo(p0.x);  g[1] = bhi(p0.x);  g[2] = blo(p0.y);  g[3] = bhi(p0.y);
      g[4] = blo(p0.z);  g[5] = bhi(p0.z);  g[6] = blo(p0.w);  g[7] = bhi(p0.w);
      g[8] = blo(p1.x);  g[9] = bhi(p1.x);  g[10] = blo(p1.y); g[11] = bhi(p1.y);
      g[12] = blo(p1.z); g[13] = bhi(p1.z); g[14] = blo(p1.w); g[15] = bhi(p1.w);
#pragma unroll
      for (int c = 0; c < C_IN; ++c) {
        const float* wk = W1 + ((size_t)k * C_IN + c) * C_OUT + d0;  // uniform -> s_load
#pragma unroll
        for (int j = 0; j < 8; ++j) acc[j] = fmaf(g[c], wk[j], acc[j]);
      }
    }

    float4 s0 = make_float4(acc[0], acc[1], acc[2], acc[3]);
    float4 s1 = make_float4(acc[4], acc[5], acc[6], acc[7]);
    reinterpret_cast<float4*>(y1 + (size_t)row * C_OUT + d0)[0] = s0;
    reinterpret_cast<float4*>(y1 + (size_t)row * C_OUT + d0)[1] = s1;
    float4 r0 = make_float4(accR[0], accR[1], accR[2], accR[3]);
    float4 r1 = make_float4(accR[4], accR[5], accR[6], accR[7]);
    reinterpret_cast<float4*>(rbuf + (size_t)row * C_OUT + d0)[0] = r0;
    reinterpret_cast<float4*>(rbuf + (size_t)row * C_OUT + d0)[1] = r1;
  }

  // wave-level stats (all 64 lanes share d0; invalid lanes contribute 0)
#pragma unroll
  for (int j = 0; j < 8; ++j) {
    float v = acc[j], s = acc[j] * acc[j];
    float vr = accR[j], sr = accR[j] * accR[j];
#pragma unroll
    for (int m = 32; m >= 1; m >>= 1) {
      v += __shfl_xor(v, m); s += __shfl_xor(s, m);
      vr += __shfl_xor(vr, m); sr += __shfl_xor(sr, m);
    }
    if (lane == 0) {
      atomicAdd(&stats[ST_SUM1 + d0 + j], v);
      atomicAdd(&stats[ST_SQ1 + d0 + j], s);
      atomicAdd(&stats[ST_SUMR + d0 + j], vr);
      atomicAdd(&stats[ST_SQR + d0 + j], sr);
    }
  }
}

// ---------------- bn1: x1b = bf16(lrelu(bn(y1))) ----------------
__global__ __launch_bounds__(256) void k_bn1(
    const float* __restrict__ y1, const float* __restrict__ stats,
    const float* __restrict__ g1, const float* __restrict__ b1,
    u16* __restrict__ x1b) {
  const int i = blockIdx.x * 256 + threadIdx.x;  // 8-float chunk index
  if (i >= NC / 8) return;
  const int d0 = (i * 8) & (C_OUT - 1);
  const float4* yp = reinterpret_cast<const float4*>(y1 + (size_t)i * 8);
  float4 a = yp[0], b = yp[1];
  float vv[8] = {a.x, a.y, a.z, a.w, b.x, b.y, b.z, b.w};
  float o[8];
#pragma unroll
  for (int j = 0; j < 8; ++j) {
    const int d = d0 + j;
    const float mean = stats[ST_SUM1 + d] * (1.0f / NROWS);
    const float var = stats[ST_SQ1 + d] * (1.0f / NROWS) - mean * mean;
    const float inv = 1.0f / sqrtf(var + EPS);
    const float x = (vv[j] - mean) * inv * g1[d] + b1[d];
    o[j] = x >= 0.f ? x : SLOPE * x;
  }
  uint4 r;
  r.x = pack2(o[0], o[1]); r.y = pack2(o[2], o[3]);
  r.z = pack2(o[4], o[5]); r.w = pack2(o[6], o[7]);
  reinterpret_cast<uint4*>(x1b)[i] = r;
}

// ---------------- conv2: gather bf16 x1, scalar f32 W2, + stats ----------------
__global__ __launch_bounds__(256, 4) void k_conv2(
    const u16* __restrict__ x1b, const int* __restrict__ nbT,
    const unsigned* __restrict__ umask, const float* __restrict__ W2,
    float* __restrict__ y2, float* __restrict__ stats) {
  const int tid = threadIdx.x;
  const int lane = tid & 63;
  const int d0 = __builtin_amdgcn_readfirstlane((tid >> 6) * 8);  // wave-uniform
  const int row = blockIdx.x * 64 + lane;
  const bool valid = row < NROWS;

  float acc[8];
#pragma unroll
  for (int j = 0; j < 8; ++j) acc[j] = 0.f;

  if (valid) {
    const unsigned um = umask[row];
#pragma unroll 2
    for (int k = 0; k < KK; ++k) {
      const int idx = nbT[(size_t)k * NROWS + row];
      const unsigned sel = 0u - ((um >> k) & 1u);
      const uint4* gp = reinterpret_cast<const uint4*>(x1b + (size_t)idx * C_OUT);
      uint4 p0 = gp[0], p1 = gp[1], p2 = gp[2], p3 = gp[3];
      p0.x &= sel; p0.y &= sel; p0.z &= sel; p0.w &= sel;
      p1.x &= sel; p1.y &= sel; p1.z &= sel; p1.w &= sel;
      p2.x &= sel; p2.y &= sel; p2.z &= sel; p2.w &= sel;
      p3.x &= sel; p3.y &= sel; p3.z &= sel; p3.w &= sel;
      float g[C_OUT];
      g[0] = blo(p0.x);  g[1] = bhi(p0.x);  g[2] = blo(p0.y);  g[3] = bhi(p0.y);
      g[4] = blo(p0.z);  g[5] = bhi(p0.z);  g[6] = blo(p0.w);  g[7] = bhi(p0.w);
      g[8] = blo(p1.x);  g[9] = bhi(p1.x);  g[10] = blo(p1.y); g[11] = bhi(p1.y);
      g[12] = blo(p1.z); g[13] = bhi(p1.z); g[14] = blo(p1.w); g[15] = bhi(p1.w);
      g[16] = blo(p2.x); g[17] = bhi(p2.x); g[18] = blo(p2.y); g[19] = bhi(p2.y);
      g[20] = blo(p2.z); g[21] = bhi(p2.z); g[22] = blo(p2.w); g[23] = bhi(p2.w);
      g[24] = blo(p3.x); g[25] = bhi(p3.x); g[26] = blo(p3.y); g[27] = bhi(p3.y);
      g[28] = blo(p3.z); g[29] = bhi(p3.z); g[30] = blo(p3.w); g[31] = bhi(p3.w);
#pragma unroll
      for (int c = 0; c < C_OUT; ++c) {
        const float* wk = W2 + ((size_t)k * C_OUT + c) * C_OUT + d0;  // uniform -> s_load
#pragma unroll
        for (int j = 0; j < 8; ++j) acc[j] = fmaf(g[c], wk[j], acc[j]);
      }
    }
    float4 s0 = make_float4(acc[0], acc[1], acc[2], acc[3]);
    float4 s1 = make_float4(acc[4], acc[5], acc[6], acc[7]);
    reinterpret_cast<float4*>(y2 + (size_t)row * C_OUT + d0)[0] = s0;
    reinterpret_cast<float4*>(y2 + (size_t)row * C_OUT + d0)[1] = s1;
  }

#pragma unroll
  for (int j = 0; j < 8; ++j) {
    float v = acc[j], s = acc[j] * acc[j];
#pragma unroll
    for (int m = 32; m >= 1; m >>= 1) {
      v += __shfl_xor(v, m); s += __shfl_xor(s, m);
    }
    if (lane == 0) {
      atomicAdd(&stats[ST_SUM2 + d0 + j], v);
      atomicAdd(&stats[ST_SQ2 + d0 + j], s);
    }
  }
}

// ---------------- out = lrelu(bn(y2) + bn(r)) ----------------
__global__ __launch_bounds__(256) void k_out(
    const float* __restrict__ y2, const float* __restrict__ rbuf,
    const float* __restrict__ stats,
    const float* __restrict__ g2, const float* __restrict__ b2,
    const float* __restrict__ gin, const float* __restrict__ bin_,
    float* __restrict__ out) {
  const int i = blockIdx.x * 256 + threadIdx.x;  // float4 index
  if (i >= NC / 4) return;
  const int d0 = (i * 4) & (C_OUT - 1);
  float4 v2 = reinterpret_cast<const float4*>(y2)[i];
  float4 vr = reinterpret_cast<const float4*>(rbuf)[i];
  float a2[4] = {v2.x, v2.y, v2.z, v2.w};
  float ar[4] = {vr.x, vr.y, vr.z, vr.w};
  float o[4];
#pragma unroll
  for (int j = 0; j < 4; ++j) {
    const int d = d0 + j;
    const float m2 = stats[ST_SUM2 + d] * (1.0f / NROWS);
    const float va2 = stats[ST_SQ2 + d] * (1.0f / NROWS) - m2 * m2;
    const float i2 = 1.0f / sqrtf(va2 + EPS);
    const float mr = stats[ST_SUMR + d] * (1.0f / NROWS);
    const float var_r = stats[ST_SQR + d] * (1.0f / NROWS) - mr * mr;
    const float ir = 1.0f / sqrtf(var_r + EPS);
    const float xa = (a2[j] - m2) * i2 * g2[d] + b2[d];
    const float xr = (ar[j] - mr) * ir * gin[d] + bin_[d];
    const float s = xa + xr;
    o[j] = s >= 0.f ? s : SLOPE * s;
  }
  reinterpret_cast<float4*>(out)[i] = make_float4(o[0], o[1], o[2], o[3]);
}

extern "C" void kernel_launch(void* const* d_in, const int* in_sizes, int n_in,
                              void* d_out, int out_size, void* d_ws, size_t ws_size,
                              hipStream_t stream) {
  (void)in_sizes; (void)n_in; (void)out_size; (void)ws_size;
  const float* features = (const float*)d_in[0];
  const int* neighbors = (const int*)d_in[1];
  const void* mask = d_in[2];
  const float* W1 = (const float*)d_in[3];
  const float* g1 = (const float*)d_in[4];
  const float* b1 = (const float*)d_in[5];
  const float* W2 = (const float*)d_in[6];
  const float* g2 = (const float*)d_in[7];
  const float* b2 = (const float*)d_in[8];
  const float* Win = (const float*)d_in[9];
  const float* gin = (const float*)d_in[10];
  const float* bin_ = (const float*)d_in[11];
  float* out = (float*)d_out;

  // ws layout (float units):
  // rbuf[NC] | stats[192 pad 256] | umask[NROWS u32] | featb[NROWS*16 u16 = NROWS*8 f]
  // | nbT[KK*NROWS i32] | x1b[NC u16 = NC/2 f]   -> total ~33.6 MB
  float* ws = (float*)d_ws;
  float* rbuf = ws;
  float* stats = ws + (size_t)NC;
  int* flag = (int*)(ws + (size_t)NC + 192);
  unsigned* umask = (unsigned*)(ws + (size_t)NC + 256);
  u16* featb = (u16*)(ws + (size_t)NC + 256 + NROWS);
  int* nbT = (int*)(ws + (size_t)NC + 256 + NROWS + (size_t)NROWS * 8);
  u16* x1b = (u16*)(ws + (size_t)NC + 256 + NROWS + (size_t)NROWS * 8 + (size_t)KK * NROWS);

  hipMemsetAsync(stats, 0, 192 * sizeof(float), stream);

  const int rowBlocks = (NROWS + 255) / 256;      // 391
  const int convBlocks = (NROWS + 63) / 64;       // 1563 (64 rows/block, 4 waves)
  const int bn1Blocks = (NC / 8 + 255) / 256;     // 1563
  const int ewBlocks = (NC / 4 + 255) / 256;      // 3125

  k_detect<<<1, 256, 0, stream>>>((const unsigned char*)mask, flag);
  k_canon<<<rowBlocks, 256, 0, stream>>>(mask, flag, neighbors, features,
                                         umask, featb, nbT);
  k_conv1<<<convBlocks, 256, 0, stream>>>(features, featb, nbT, umask, W1, Win,
                                          out /*y1*/, rbuf, stats);
  k_bn1<<<bn1Blocks, 256, 0, stream>>>(out /*y1*/, stats, g1, b1, x1b);
  k_conv2<<<convBlocks, 256, 0, stream>>>(x1b, nbT, umask, W2, out /*y2*/, stats);
  k_out<<<ewBlocks, 256, 0, stream>>>(out /*y2*/, rbuf, stats, g2, b2, gin, bin_, out);
}